// Round 5
// baseline (408.549 us; speedup 1.0000x reference)
//
#include <hip/hip_runtime.h>
#include <hip/hip_bf16.h>

#define Bdim 64
#define Tdim 96
#define Pdim 256
#define Hdim 128
#define Gdim 512   // 4*H
#define Odim 24
#define BH   32    // batches per stream (two streams per block)
#define WROW 132   // h row length in f16 elems (128+4 pad = 264B rows; stride 66 dw ≡ 2 mod 32 -> free 2-way bank pattern)

typedef _Float16 f16x8 __attribute__((ext_vector_type(8)));
typedef float    f32x16 __attribute__((ext_vector_type(16)));
typedef float    f32x2  __attribute__((ext_vector_type(2)));

union H8 { uint2 u2[2]; unsigned short s[8]; _Float16 h[8]; f16x8 v; };
union HS { _Float16 h; unsigned short s; };

__device__ __forceinline__ float exp2_fast(float x) {
#if __has_builtin(__builtin_amdgcn_exp2f)
    return __builtin_amdgcn_exp2f(x);
#else
    return __expf(x * 0.6931471805599453f);
#endif
}

// One block per point p (grid=256, 1024 threads = 16 waves). Wave w owns r' rows
// [32w, 32w+32); r' = 4*k + gate (i,f,g,o) so regs 4q..4q+3 of a lane hold all 4
// gates of one (b,k). B=64 split into two 32-batch streams processed in the SAME
// phase; the epilogue pairs the streams: float2 packed math (v_pk_*_f32) and one
// shared rcp per denominator pair (rcp(d0 d1) -> 1/d0, 1/d1 via 2 muls). Trans
// count: 6 per (b,k) (5 exp2 + 1 paired rcp). A-fragments (W_hh prescaled by
// log2e, 2*log2e for g) shared by both streams. gx fused as a 9th MFMA K-step.
// Cell state in 2*log2e-scaled domain. One barrier per step (write to buf^1).
__global__ __launch_bounds__(1024, 4)
void lstm_fused(const float* __restrict__ x,
                const float* __restrict__ W_ih,
                const float* __restrict__ W_hh,
                const float* __restrict__ b_ih,
                const float* __restrict__ b_hh,
                const float* __restrict__ W_fc,
                const float* __restrict__ b_fc,
                float* __restrict__ out)
{
    __shared__ unsigned short hs[2][2][BH * WROW];  // [stream][buf][b*WROW+k], f16 bits

    const int p   = blockIdx.x;
    const int tid = threadIdx.x;
    const int w   = tid >> 6;    // wave 0..15
    const int l31 = tid & 31;
    const int hi  = (tid >> 5) & 1;

    const float L1 = 1.4426950408889634f;  // log2(e)
    const float L2 = 2.0f * L1;

    for (int i = tid; i < 2 * 2 * BH * WROW; i += 1024) ((unsigned short*)hs)[i] = 0;

    // ---- preload shared A fragments (time-invariant): W_hh rows + gx row ----
    f16x8 afr[9];
    {
        const int rp   = w * 32 + l31;                // r'
        const int orow = ((rp & 3) << 7) | (rp >> 2); // gate*128 + k
        const float sc = ((rp & 3) == 2) ? L2 : L1;   // g gate: 2*log2e
        const float* rowp = W_hh + (size_t)p * Gdim * Hdim + (size_t)orow * Hdim;
        #pragma unroll
        for (int ks = 0; ks < 8; ++ks) {
            int k0 = ks * 16 + hi * 8;
            float4 va = *(const float4*)(rowp + k0);
            float4 vb = *(const float4*)(rowp + k0 + 4);
            H8 u;
            u.h[0] = (_Float16)(sc * va.x); u.h[1] = (_Float16)(sc * va.y);
            u.h[2] = (_Float16)(sc * va.z); u.h[3] = (_Float16)(sc * va.w);
            u.h[4] = (_Float16)(sc * vb.x); u.h[5] = (_Float16)(sc * vb.y);
            u.h[6] = (_Float16)(sc * vb.z); u.h[7] = (_Float16)(sc * vb.w);
            afr[ks] = u.v;
        }
        H8 u9;
        #pragma unroll
        for (int j = 0; j < 8; ++j) u9.s[j] = 0;
        if (hi == 0) {
            u9.h[0] = (_Float16)(sc * W_ih[(size_t)p * Gdim + orow]);            // k=128: * x
            u9.h[1] = (_Float16)(sc * (b_ih[(size_t)p * Gdim + orow] +
                                       b_hh[(size_t)p * Gdim + orow]));          // k=129: * 1
        }
        afr[8] = u9.v;
    }

    // loop-invariant zero accumulator (C of the first MFMA) — kills per-step acc init
    f32x16 zacc;
    #pragma unroll
    for (int j = 0; j < 16; ++j) zacc[j] = 0.f;

    f32x2 cre[4];   // scaled-domain cell state, paired across streams
    #pragma unroll
    for (int q = 0; q < 4; ++q) cre[q] = f32x2{0.f, 0.f};

    const float* xp0 = x + (size_t)((0 * BH + l31) * Tdim) * Pdim + p;
    const float* xp1 = x + (size_t)((1 * BH + l31) * Tdim) * Pdim + p;
    float xv0 = xp0[0];
    float xv1 = xp1[0];

    const int lbase = l31 * (WROW * 2);

    __syncthreads();

    auto dostep = [&](const int cur, const int t) {
        float xn0 = 0.f, xn1 = 0.f;
        if (t + 1 < Tdim) {
            xn0 = xp0[(size_t)(t + 1) * Pdim];
            xn1 = xp1[(size_t)(t + 1) * Pdim];
        }

        // ---- GEMM both streams, shared A-fragments ----
        const char* h0 = (const char*)hs[0][cur];
        const char* h1 = (const char*)hs[1][cur];
        f32x16 a0, a1;
        #pragma unroll
        for (int ks = 0; ks < 8; ++ks) {
            int boff = lbase + ks * 32 + hi * 16;
            H8 b0, b1;
            b0.u2[0] = *(const uint2*)(h0 + boff);
            b0.u2[1] = *(const uint2*)(h0 + boff + 8);
            b1.u2[0] = *(const uint2*)(h1 + boff);
            b1.u2[1] = *(const uint2*)(h1 + boff + 8);
            a0 = __builtin_amdgcn_mfma_f32_32x32x16_f16(afr[ks], b0.v, ks ? a0 : zacc, 0, 0, 0);
            a1 = __builtin_amdgcn_mfma_f32_32x32x16_f16(afr[ks], b1.v, ks ? a1 : zacc, 0, 0, 0);
        }
        {   // 9th K-step: gx = x*W_ih + bias
            H8 bg0, bg1;
            #pragma unroll
            for (int j = 0; j < 8; ++j) { bg0.s[j] = 0; bg1.s[j] = 0; }
            if (hi == 0) {
                bg0.h[0] = (_Float16)xv0; bg0.h[1] = (_Float16)1.0f;
                bg1.h[0] = (_Float16)xv1; bg1.h[1] = (_Float16)1.0f;
            }
            a0 = __builtin_amdgcn_mfma_f32_32x32x16_f16(afr[8], bg0.v, a0, 0, 0, 0);
            a1 = __builtin_amdgcn_mfma_f32_32x32x16_f16(afr[8], bg1.v, a1, 0, 0, 0);
        }

        // ---- epilogue, stream-paired (float2) ----
        unsigned short* w0 = hs[0][cur ^ 1];
        unsigned short* w1 = hs[1][cur ^ 1];
        #pragma unroll
        for (int q = 0; q < 4; ++q) {
            f32x2 yi = {a0[4 * q + 0], a1[4 * q + 0]};
            f32x2 yf = {a0[4 * q + 1], a1[4 * q + 1]};
            f32x2 yg = {a0[4 * q + 2], a1[4 * q + 2]};   // prescaled by 2*log2e
            f32x2 yo = {a0[4 * q + 3], a1[4 * q + 3]};
            f32x2 Ef = {exp2_fast(-yf.x), exp2_fast(-yf.y)};
            f32x2 Ei = {exp2_fast(-yi.x), exp2_fast(-yi.y)};
            f32x2 Eg = {exp2_fast(yg.x),  exp2_fast(yg.y)};
            f32x2 t1 = Ef + 1.0f;
            f32x2 t2 = Ei + 1.0f;
            f32x2 t3 = Eg + 1.0f;
            f32x2 t4 = Eg - 1.0f;
            f32x2 den = (t1 * t2) * t3;
            f32x2 num = (cre[q] * t2) * t3 + (L2 * t4) * t1;
            float D = den.x * den.y;
            float r = __builtin_amdgcn_rcpf(D);
            f32x2 inv = {r * den.y, r * den.x};
            f32x2 cn  = num * inv;
            cn.x = fminf(30.0f, fmaxf(-30.0f, cn.x));
            cn.y = fminf(30.0f, fmaxf(-30.0f, cn.y));
            cre[q] = cn;
            f32x2 Eo = {exp2_fast(-yo.x), exp2_fast(-yo.y)};
            f32x2 Ec = {exp2_fast(cn.x),  exp2_fast(cn.y)};
            f32x2 d2 = (Eo + 1.0f) * (Ec + 1.0f);
            float D2 = d2.x * d2.y;
            float r2 = __builtin_amdgcn_rcpf(D2);
            f32x2 j2 = {r2 * d2.y, r2 * d2.x};
            f32x2 hv = (Ec - 1.0f) * j2;
            HS ha; ha.h = (_Float16)hv.x;
            HS hb; hb.h = (_Float16)hv.y;
            int idx = l31 * WROW + (w * 8 + 2 * q + hi);
            w0[idx] = ha.s;
            w1[idx] = hb.s;
        }

        __syncthreads();
        xv0 = xn0; xv1 = xn1;
    };

    for (int t = 0; t < Tdim; t += 2) {
        dostep(0, t);       // reads buf0, writes buf1
        dostep(1, t + 1);   // reads buf1, writes buf0
    }
    // Tdim even -> final h sits in hs[s][0]

    // ---- FC: out[b][o][p] = sum_k W_fc[p][o][k]*h[b][k] + b_fc[p][o] ----
    const float* wfc = W_fc + (size_t)p * Odim * Hdim;
    const float* bfc = b_fc + (size_t)p * Odim;
    for (int i = tid; i < Bdim * Odim; i += 1024) {
        int o = i % Odim;
        int b = i / Odim;            // global batch 0..63
        const unsigned short* hr = (b < BH) ? (hs[0][0] + b * WROW)
                                            : (hs[1][0] + (b - BH) * WROW);
        float s = bfc[o];
        const float* wr = wfc + o * Hdim;
        #pragma unroll 8
        for (int k2 = 0; k2 < Hdim; ++k2) {
            HS s2; s2.s = hr[k2];
            s = __builtin_fmaf(wr[k2], (float)s2.h, s);
        }
        out[(size_t)b * Odim * Pdim + (size_t)o * Pdim + p] = s;
    }
}

extern "C" void kernel_launch(void* const* d_in, const int* in_sizes, int n_in,
                              void* d_out, int out_size, void* d_ws, size_t ws_size,
                              hipStream_t stream) {
    const float* x    = (const float*)d_in[0];
    const float* W_ih = (const float*)d_in[1];
    const float* W_hh = (const float*)d_in[2];
    const float* b_ih = (const float*)d_in[3];
    const float* b_hh = (const float*)d_in[4];
    const float* W_fc = (const float*)d_in[5];
    const float* b_fc = (const float*)d_in[6];
    float* out = (float*)d_out;

    lstm_fused<<<dim3(Pdim), dim3(1024), 0, stream>>>(x, W_ih, W_hh, b_ih, b_hh, W_fc, b_fc, out);
}

// Round 6
// 399.246 us; speedup vs baseline: 1.0233x; 1.0233x over previous
//
#include <hip/hip_runtime.h>
#include <hip/hip_bf16.h>

#define Bdim 64
#define Tdim 96
#define Pdim 256
#define Hdim 128
#define Gdim 512   // 4*H
#define Odim 24
#define BH   32    // batches per stream (two streams per block)
#define WROW 132   // h row length in f16 elems (264B rows; stride 66 dw == 2 mod 32 -> free 2-way bank pattern)

typedef _Float16 f16x8 __attribute__((ext_vector_type(8)));
typedef float    f32x16 __attribute__((ext_vector_type(16)));
typedef float    f32x2  __attribute__((ext_vector_type(2)));

union H8 { uint2 u2[2]; unsigned short s[8]; _Float16 h[8]; f16x8 v; };
union HS { _Float16 h; unsigned short s; };

__device__ __forceinline__ float exp2_fast(float x) {
#if __has_builtin(__builtin_amdgcn_exp2f)
    return __builtin_amdgcn_exp2f(x);
#else
    return __expf(x * 0.6931471805599453f);
#endif
}

#define SGB __builtin_amdgcn_sched_group_barrier

// One block per point p (grid=256, 1024 threads = 16 waves). Wave w owns r' rows
// [32w,32w+32); r' = 4*k+gate (i,f,g,o): regs 4q..4q+3 of a lane = 4 gates of one
// (b,k). B=64 in two 32-batch streams, half a step apart. Each phase SOURCE-
// INTERLEAVES one stream's gemm (ds_read + MFMA, 2-ahead) with the other
// stream's transcendental epilogue, so the per-CU LDS pipe (~3000 cy/step) and
// the VALU pipe (~4350 cy/step) overlap instead of serializing (R2/R4/R5 all
// pinned at ~8950 cy/step = sum). LDS buffers are distinct __shared__ arrays ->
// provably no alias -> compiler free to honor the interleaved order; a
// sched_group_barrier pattern pins DS/MFMA/VALU mixing. Math identical to R5:
// log2e-prescaled weights (2log2e for g), gx as 9th MFMA K-step, scaled-domain
// cell state, paired-rcp epilogue (6 trans per (b,k)).
__global__ __launch_bounds__(1024, 4)
void lstm_fused(const float* __restrict__ x,
                const float* __restrict__ W_ih,
                const float* __restrict__ W_hh,
                const float* __restrict__ b_ih,
                const float* __restrict__ b_hh,
                const float* __restrict__ W_fc,
                const float* __restrict__ b_fc,
                float* __restrict__ out)
{
    __shared__ unsigned short hb0[2][BH * WROW];  // stream0 h, double-buffered
    __shared__ unsigned short hb1[2][BH * WROW];  // stream1 h, double-buffered

    const int p   = blockIdx.x;
    const int tid = threadIdx.x;
    const int w   = tid >> 6;    // wave 0..15
    const int l31 = tid & 31;
    const int hi  = (tid >> 5) & 1;

    const float L1 = 1.4426950408889634f;  // log2(e)
    const float L2 = 2.0f * L1;

    for (int i = tid; i < 2 * BH * WROW; i += 1024) {
        hb0[0][i < BH * WROW ? i : i - BH * WROW] = 0;  // avoid UB-ish flat cast
    }
    for (int i = tid; i < 2 * BH * WROW; i += 1024) {
        ((unsigned short*)hb0)[i] = 0;
    }
    for (int i = tid; i < 2 * BH * WROW; i += 1024) {
        ((unsigned short*)hb1)[i] = 0;
    }

    // ---- preload shared A fragments (time-invariant): W_hh rows + gx row ----
    f16x8 afr[9];
    {
        const int rp   = w * 32 + l31;                // r'
        const int orow = ((rp & 3) << 7) | (rp >> 2); // gate*128 + k
        const float sc = ((rp & 3) == 2) ? L2 : L1;   // g gate: 2*log2e
        const float* rowp = W_hh + (size_t)p * Gdim * Hdim + (size_t)orow * Hdim;
        #pragma unroll
        for (int ks = 0; ks < 8; ++ks) {
            int k0 = ks * 16 + hi * 8;
            float4 va = *(const float4*)(rowp + k0);
            float4 vb = *(const float4*)(rowp + k0 + 4);
            H8 u;
            u.h[0] = (_Float16)(sc * va.x); u.h[1] = (_Float16)(sc * va.y);
            u.h[2] = (_Float16)(sc * va.z); u.h[3] = (_Float16)(sc * va.w);
            u.h[4] = (_Float16)(sc * vb.x); u.h[5] = (_Float16)(sc * vb.y);
            u.h[6] = (_Float16)(sc * vb.z); u.h[7] = (_Float16)(sc * vb.w);
            afr[ks] = u.v;
        }
        H8 u9;
        #pragma unroll
        for (int j = 0; j < 8; ++j) u9.s[j] = 0;
        if (hi == 0) {
            u9.h[0] = (_Float16)(sc * W_ih[(size_t)p * Gdim + orow]);
            u9.h[1] = (_Float16)(sc * (b_ih[(size_t)p * Gdim + orow] +
                                       b_hh[(size_t)p * Gdim + orow]));
        }
        afr[8] = u9.v;
    }

    const int lbase = l31 * (WROW * 2);

    // LDS fragment load for one ks tile
    auto ldh = [&](const char* hb, int ks) -> H8 {
        H8 r;
        int boff = lbase + ks * 32 + hi * 16;
        r.u2[0] = *(const uint2*)(hb + boff);
        r.u2[1] = *(const uint2*)(hb + boff + 8);
        return r;
    };

    // epilogue for q-pair (q=2j, 2j+1) of one stream: acc -> new c, h -> wb
    auto ep_pair = [&](const f32x16& a, int j, f32x2* cr, unsigned short* wb) {
        f32x2 yi = {a[8 * j + 0], a[8 * j + 4]};
        f32x2 yf = {a[8 * j + 1], a[8 * j + 5]};
        f32x2 yg = {a[8 * j + 2], a[8 * j + 6]};   // prescaled by 2*log2e
        f32x2 yo = {a[8 * j + 3], a[8 * j + 7]};
        f32x2 Ef = {exp2_fast(-yf.x), exp2_fast(-yf.y)};
        f32x2 Ei = {exp2_fast(-yi.x), exp2_fast(-yi.y)};
        f32x2 Eg = {exp2_fast(yg.x),  exp2_fast(yg.y)};
        f32x2 t1 = Ef + 1.0f;
        f32x2 t2 = Ei + 1.0f;
        f32x2 t3 = Eg + 1.0f;
        f32x2 t4 = Eg - 1.0f;
        f32x2 den = (t1 * t2) * t3;
        f32x2 num = (cr[j] * t2) * t3 + (L2 * t4) * t1;
        float D = den.x * den.y;
        float r = __builtin_amdgcn_rcpf(D);
        f32x2 inv = {r * den.y, r * den.x};
        f32x2 cn  = num * inv;
        cn.x = fminf(30.0f, fmaxf(-30.0f, cn.x));
        cn.y = fminf(30.0f, fmaxf(-30.0f, cn.y));
        cr[j] = cn;
        f32x2 Eo = {exp2_fast(-yo.x), exp2_fast(-yo.y)};
        f32x2 Ec = {exp2_fast(cn.x),  exp2_fast(cn.y)};
        f32x2 d2 = (Eo + 1.0f) * (Ec + 1.0f);
        float D2 = d2.x * d2.y;
        float r2 = __builtin_amdgcn_rcpf(D2);
        f32x2 j2 = {r2 * d2.y, r2 * d2.x};
        f32x2 hv = (Ec - 1.0f) * j2;
        HS ha; ha.h = (_Float16)hv.x;
        HS hc; hc.h = (_Float16)hv.y;
        int base = l31 * WROW + (w * 8 + 4 * j + hi);
        wb[base]     = ha.s;   // q = 2j
        wb[base + 2] = hc.s;   // q = 2j+1
    };

    // one phase: gemm of one stream (rb -> aw) interleaved with epilogue of the
    // other stream (ar -> wb). doGemm/doEp are compile-time at each call site.
    auto phase = [&](const unsigned short* rb, unsigned short* wb,
                     f32x16& aw, const f32x16& ar, f32x2* cr, float xv,
                     bool doGemm, bool doEp) {
        if (doGemm) {
            const char* hb = (const char*)rb;
            H8 f0 = ldh(hb, 0), f1 = ldh(hb, 1);
            H8 f2 = ldh(hb, 2), f3 = ldh(hb, 3);
            f32x16 z;
            #pragma unroll
            for (int j = 0; j < 16; ++j) z[j] = 0.f;
            f32x16 a;
            a = __builtin_amdgcn_mfma_f32_32x32x16_f16(afr[0], f0.v, z, 0, 0, 0);
            a = __builtin_amdgcn_mfma_f32_32x32x16_f16(afr[1], f1.v, a, 0, 0, 0);
            if (doEp) ep_pair(ar, 0, cr, wb);
            H8 f4 = ldh(hb, 4), f5 = ldh(hb, 5);
            a = __builtin_amdgcn_mfma_f32_32x32x16_f16(afr[2], f2.v, a, 0, 0, 0);
            a = __builtin_amdgcn_mfma_f32_32x32x16_f16(afr[3], f3.v, a, 0, 0, 0);
            if (doEp) ep_pair(ar, 1, cr, wb);
            H8 f6 = ldh(hb, 6), f7 = ldh(hb, 7);
            a = __builtin_amdgcn_mfma_f32_32x32x16_f16(afr[4], f4.v, a, 0, 0, 0);
            a = __builtin_amdgcn_mfma_f32_32x32x16_f16(afr[5], f5.v, a, 0, 0, 0);
            a = __builtin_amdgcn_mfma_f32_32x32x16_f16(afr[6], f6.v, a, 0, 0, 0);
            a = __builtin_amdgcn_mfma_f32_32x32x16_f16(afr[7], f7.v, a, 0, 0, 0);
            H8 bg;
            #pragma unroll
            for (int j = 0; j < 8; ++j) bg.s[j] = 0;
            if (hi == 0) { bg.h[0] = (_Float16)xv; bg.h[1] = (_Float16)1.0f; }
            a = __builtin_amdgcn_mfma_f32_32x32x16_f16(afr[8], bg.v, a, 0, 0, 0);
            aw = a;
            if (doEp) {
                // pin the mixed DS/MFMA/VALU order (best-effort)
                SGB(0x100, 2, 0);   // ds_read ks0,1
                SGB(0x008, 1, 0);   // mfma
                SGB(0x402, 25, 0);  // ep chunk0 first half (VALU|TRANS)
                SGB(0x100, 2, 0);   // ds_read ks2,3
                SGB(0x008, 1, 0);
                SGB(0x402, 25, 0);  // ep chunk0 rest
                SGB(0x200, 2, 0);   // ds_write chunk0
                SGB(0x100, 2, 0);   // ds_read ks4,5
                SGB(0x008, 2, 0);
                SGB(0x402, 25, 0);  // ep chunk1 first half
                SGB(0x100, 2, 0);   // ds_read ks6,7
                SGB(0x008, 2, 0);
                SGB(0x402, 25, 0);  // ep chunk1 rest
                SGB(0x200, 2, 0);   // ds_write chunk1
                SGB(0x008, 3, 0);   // tail mfma + gx
            }
        } else if (doEp) {
            ep_pair(ar, 0, cr, wb);
            ep_pair(ar, 1, cr, wb);
        }
    };

    f32x2 cre0[2] = {f32x2{0.f, 0.f}, f32x2{0.f, 0.f}};
    f32x2 cre1[2] = {f32x2{0.f, 0.f}, f32x2{0.f, 0.f}};
    f32x16 acc0, acc1;
    #pragma unroll
    for (int j = 0; j < 16; ++j) { acc0[j] = 0.f; acc1[j] = 0.f; }

    const float* xp0 = x + (size_t)((0 * BH + l31) * Tdim) * Pdim + p;
    const float* xp1 = x + (size_t)((1 * BH + l31) * Tdim) * Pdim + p;
    float xv1 = xp1[0];

    __syncthreads();

    // phase A(0): gemm_s0(0) only (reads zeros), no epilogue yet
    {
        float xv0 = xp0[0];
        phase(hb0[0], hb1[0], acc0, acc1, cre1, xv0, true, false);
    }
    __syncthreads();

    for (int t = 0; t < Tdim; ++t) {
        const int P  = t & 1;
        const int tn = (t + 1 < Tdim) ? (t + 1) : t;
        float xn0 = xp0[(size_t)tn * Pdim];   // for gemm_s0(t+1)

        // phase B(t): gemm_s1(t) reads hb1[P]  ||  ep_s0(t) writes hb0[P^1]
        phase(hb1[P], hb0[P ^ 1], acc1, acc0, cre0, xv1, true, true);
        __syncthreads();

        float xn1 = xp1[(size_t)tn * Pdim];   // for gemm_s1(t+1)
        if (t + 1 < Tdim) {
            // phase A(t+1): gemm_s0(t+1) reads hb0[P^1] || ep_s1(t) writes hb1[P^1]
            phase(hb0[P ^ 1], hb1[P ^ 1], acc0, acc1, cre1, xn0, true, true);
        } else {
            // final: ep_s1(95) only -> hb1[0]
            phase(hb0[P ^ 1], hb1[P ^ 1], acc0, acc1, cre1, 0.f, false, true);
        }
        __syncthreads();
        xv1 = xn1;
    }
    // final h: stream0 in hb0[0], stream1 in hb1[0]

    // ---- FC: out[b][o][p] = sum_k W_fc[p][o][k]*h[b][k] + b_fc[p][o] ----
    const float* wfc = W_fc + (size_t)p * Odim * Hdim;
    const float* bfc = b_fc + (size_t)p * Odim;
    for (int i = tid; i < Bdim * Odim; i += 1024) {
        int o = i % Odim;
        int b = i / Odim;            // global batch 0..63
        const unsigned short* hr = (b < BH) ? (hb0[0] + b * WROW)
                                            : (hb1[0] + (b - BH) * WROW);
        float s = bfc[o];
        const float* wr = wfc + o * Hdim;
        #pragma unroll 8
        for (int k2 = 0; k2 < Hdim; ++k2) {
            HS s2; s2.s = hr[k2];
            s = __builtin_fmaf(wr[k2], (float)s2.h, s);
        }
        out[(size_t)b * Odim * Pdim + (size_t)o * Pdim + p] = s;
    }
}

extern "C" void kernel_launch(void* const* d_in, const int* in_sizes, int n_in,
                              void* d_out, int out_size, void* d_ws, size_t ws_size,
                              hipStream_t stream) {
    const float* x    = (const float*)d_in[0];
    const float* W_ih = (const float*)d_in[1];
    const float* W_hh = (const float*)d_in[2];
    const float* b_ih = (const float*)d_in[3];
    const float* b_hh = (const float*)d_in[4];
    const float* W_fc = (const float*)d_in[5];
    const float* b_fc = (const float*)d_in[6];
    float* out = (float*)d_out;

    lstm_fused<<<dim3(Pdim), dim3(1024), 0, stream>>>(x, W_ih, W_hh, b_ih, b_hh, W_fc, b_fc, out);
}

// Round 7
// 390.933 us; speedup vs baseline: 1.0451x; 1.0213x over previous
//
#include <hip/hip_runtime.h>
#include <hip/hip_bf16.h>

#define Bdim 64
#define Tdim 96
#define Pdim 256
#define Hdim 128
#define Gdim 512   // 4*H
#define Odim 24
#define BH   32    // batches per stream (two streams per block)

typedef _Float16 f16x8 __attribute__((ext_vector_type(8)));
typedef float    f32x16 __attribute__((ext_vector_type(16)));
typedef float    f32x2  __attribute__((ext_vector_type(2)));

union H8 { uint4 u4; unsigned short s[8]; _Float16 h[8]; f16x8 v; };
union HS { _Float16 h; unsigned short s; };

__device__ __forceinline__ float exp2_fast(float x) {
#if __has_builtin(__builtin_amdgcn_exp2f)
    return __builtin_amdgcn_exp2f(x);
#else
    return __expf(x * 0.6931471805599453f);
#endif
}

// One block per point p (grid=256, 1024 threads = 16 waves). Wave w owns r' rows
// [32w,32w+32); r' = 4*k+gate (i,f,g,o): regs 4q..4q+3 of a lane = 4 gates of one
// (b,k). B=64 in two 32-batch streams, half a step apart (2 phases/step).
//
// h storage (THE fix this round): row b = 256 B = 16 chunks of 16 B, chunk c
// stored at position c ^ (b & 15)  (XOR swizzle, no padding). The gemm read of
// chunk c = 2ks+hi by lane b=l31 is ONE aligned ds_read_b128 at dword offset
// 64*l31 + 4*(c^(l31&15)); pos mod 8 is an XOR-bijection of l31 -> exactly 8
// lanes per 4-bank group per wave64 = perfectly balanced banks, 8 cy/read.
// (Old layout: 264 B rows -> stride 66 dw = 2 mod 32 -> EVEN BANKS ONLY, 2x LDS
// time on the kernel's dominant traffic stream + 2x b64 issue count.)
//
// Math as R5/R6: log2e-prescaled weights (2log2e for g), gx fused as 9th MFMA
// K-step, scaled-domain cell state, paired-rcp epilogue (6 trans per (b,k)).
__global__ __launch_bounds__(1024, 4)
void lstm_fused(const float* __restrict__ x,
                const float* __restrict__ W_ih,
                const float* __restrict__ W_hh,
                const float* __restrict__ b_ih,
                const float* __restrict__ b_hh,
                const float* __restrict__ W_fc,
                const float* __restrict__ b_fc,
                float* __restrict__ out)
{
    __shared__ unsigned short hb0[2][BH * Hdim];  // stream0 h, double-buffered, swizzled
    __shared__ unsigned short hb1[2][BH * Hdim];  // stream1 h, double-buffered, swizzled

    const int p   = blockIdx.x;
    const int tid = threadIdx.x;
    const int w   = tid >> 6;    // wave 0..15
    const int l31 = tid & 31;
    const int hi  = (tid >> 5) & 1;

    const float L1 = 1.4426950408889634f;  // log2(e)
    const float L2 = 2.0f * L1;

    for (int i = tid; i < 2 * BH * Hdim; i += 1024) ((unsigned short*)hb0)[i] = 0;
    for (int i = tid; i < 2 * BH * Hdim; i += 1024) ((unsigned short*)hb1)[i] = 0;

    // ---- preload shared A fragments (time-invariant): W_hh rows + gx row ----
    f16x8 afr[9];
    {
        const int rp   = w * 32 + l31;                // r'
        const int orow = ((rp & 3) << 7) | (rp >> 2); // gate*128 + k
        const float sc = ((rp & 3) == 2) ? L2 : L1;   // g gate: 2*log2e
        const float* rowp = W_hh + (size_t)p * Gdim * Hdim + (size_t)orow * Hdim;
        #pragma unroll
        for (int ks = 0; ks < 8; ++ks) {
            int k0 = ks * 16 + hi * 8;
            float4 va = *(const float4*)(rowp + k0);
            float4 vb = *(const float4*)(rowp + k0 + 4);
            H8 u;
            u.h[0] = (_Float16)(sc * va.x); u.h[1] = (_Float16)(sc * va.y);
            u.h[2] = (_Float16)(sc * va.z); u.h[3] = (_Float16)(sc * va.w);
            u.h[4] = (_Float16)(sc * vb.x); u.h[5] = (_Float16)(sc * vb.y);
            u.h[6] = (_Float16)(sc * vb.z); u.h[7] = (_Float16)(sc * vb.w);
            afr[ks] = u.v;
        }
        H8 u9;
        #pragma unroll
        for (int j = 0; j < 8; ++j) u9.s[j] = 0;
        if (hi == 0) {
            u9.h[0] = (_Float16)(sc * W_ih[(size_t)p * Gdim + orow]);
            u9.h[1] = (_Float16)(sc * (b_ih[(size_t)p * Gdim + orow] +
                                       b_hh[(size_t)p * Gdim + orow]));
        }
        afr[8] = u9.v;
    }

    // swizzled ds_read_b128: row l31, chunk c = 2ks+hi
    auto ldh = [&](const unsigned short* hb, int ks) -> H8 {
        H8 r;
        int c   = ks * 2 + hi;
        int off = (l31 << 8) + ((c ^ (l31 & 15)) << 4);   // bytes
        r.u4 = *(const uint4*)((const char*)hb + off);
        return r;
    };

    // epilogue for q-pair (q=2j, 2j+1) of one stream: acc -> new c, h -> wb (swizzled)
    auto ep_pair = [&](const f32x16& a, int j, f32x2* cr, unsigned short* wb) {
        f32x2 yi = {a[8 * j + 0], a[8 * j + 4]};
        f32x2 yf = {a[8 * j + 1], a[8 * j + 5]};
        f32x2 yg = {a[8 * j + 2], a[8 * j + 6]};   // prescaled by 2*log2e
        f32x2 yo = {a[8 * j + 3], a[8 * j + 7]};
        f32x2 Ef = {exp2_fast(-yf.x), exp2_fast(-yf.y)};
        f32x2 Ei = {exp2_fast(-yi.x), exp2_fast(-yi.y)};
        f32x2 Eg = {exp2_fast(yg.x),  exp2_fast(yg.y)};
        f32x2 t1 = Ef + 1.0f;
        f32x2 t2 = Ei + 1.0f;
        f32x2 t3 = Eg + 1.0f;
        f32x2 t4 = Eg - 1.0f;
        f32x2 den = (t1 * t2) * t3;
        f32x2 num = (cr[j] * t2) * t3 + (L2 * t4) * t1;
        float D = den.x * den.y;
        float r = __builtin_amdgcn_rcpf(D);
        f32x2 inv = {r * den.y, r * den.x};
        f32x2 cn  = num * inv;
        cn.x = __builtin_amdgcn_fmed3f(cn.x, -30.0f, 30.0f);
        cn.y = __builtin_amdgcn_fmed3f(cn.y, -30.0f, 30.0f);
        cr[j] = cn;
        f32x2 Eo = {exp2_fast(-yo.x), exp2_fast(-yo.y)};
        f32x2 Ec = {exp2_fast(cn.x),  exp2_fast(cn.y)};
        f32x2 d2 = (Eo + 1.0f) * (Ec + 1.0f);
        float D2 = d2.x * d2.y;
        float r2 = __builtin_amdgcn_rcpf(D2);
        f32x2 j2 = {r2 * d2.y, r2 * d2.x};
        f32x2 hv = (Ec - 1.0f) * j2;
        HS ha; ha.h = (_Float16)hv.x;
        HS hc; hc.h = (_Float16)hv.y;
        // k = w*8 + 4j + hi (+2); chunk = w -> swizzled pos = w ^ (l31&15)
        int base = (l31 << 7) + ((w ^ (l31 & 15)) << 3) + 4 * j + hi;
        wb[base]     = ha.s;   // q = 2j
        wb[base + 2] = hc.s;   // q = 2j+1
    };

    // one phase: gemm of one stream (rb -> acc, in place) interleaved with the
    // epilogue of the other stream (ar -> wb). doGemm/doEp compile-time per site.
    auto phase = [&](const unsigned short* rb, unsigned short* wb,
                     f32x16& acc, const f32x16& ar, f32x2* cr, float xv,
                     bool doGemm, bool doEp) {
        if (doGemm) {
            H8 f0 = ldh(rb, 0), f1 = ldh(rb, 1);
            H8 f2 = ldh(rb, 2), f3 = ldh(rb, 3);
            f32x16 z;
            #pragma unroll
            for (int j = 0; j < 16; ++j) z[j] = 0.f;
            acc = __builtin_amdgcn_mfma_f32_32x32x16_f16(afr[0], f0.v, z, 0, 0, 0);
            acc = __builtin_amdgcn_mfma_f32_32x32x16_f16(afr[1], f1.v, acc, 0, 0, 0);
            if (doEp) ep_pair(ar, 0, cr, wb);
            H8 f4 = ldh(rb, 4), f5 = ldh(rb, 5);
            acc = __builtin_amdgcn_mfma_f32_32x32x16_f16(afr[2], f2.v, acc, 0, 0, 0);
            acc = __builtin_amdgcn_mfma_f32_32x32x16_f16(afr[3], f3.v, acc, 0, 0, 0);
            if (doEp) ep_pair(ar, 1, cr, wb);
            H8 f6 = ldh(rb, 6), f7 = ldh(rb, 7);
            acc = __builtin_amdgcn_mfma_f32_32x32x16_f16(afr[4], f4.v, acc, 0, 0, 0);
            acc = __builtin_amdgcn_mfma_f32_32x32x16_f16(afr[5], f5.v, acc, 0, 0, 0);
            acc = __builtin_amdgcn_mfma_f32_32x32x16_f16(afr[6], f6.v, acc, 0, 0, 0);
            acc = __builtin_amdgcn_mfma_f32_32x32x16_f16(afr[7], f7.v, acc, 0, 0, 0);
            H8 bg;
            #pragma unroll
            for (int j = 0; j < 8; ++j) bg.s[j] = 0;
            if (hi == 0) { bg.h[0] = (_Float16)xv; bg.h[1] = (_Float16)1.0f; }
            acc = __builtin_amdgcn_mfma_f32_32x32x16_f16(afr[8], bg.v, acc, 0, 0, 0);
        } else if (doEp) {
            ep_pair(ar, 0, cr, wb);
            ep_pair(ar, 1, cr, wb);
        }
    };

    f32x2 cre0[2] = {f32x2{0.f, 0.f}, f32x2{0.f, 0.f}};
    f32x2 cre1[2] = {f32x2{0.f, 0.f}, f32x2{0.f, 0.f}};
    f32x16 acc0, acc1;
    #pragma unroll
    for (int j = 0; j < 16; ++j) { acc0[j] = 0.f; acc1[j] = 0.f; }

    const float* xp0 = x + (size_t)((0 * BH + l31) * Tdim) * Pdim + p;
    const float* xp1 = x + (size_t)((1 * BH + l31) * Tdim) * Pdim + p;
    float xv1 = xp1[0];

    __syncthreads();

    // prologue: gemm_s0(0) only (reads zeros)
    {
        float xv0 = xp0[0];
        phase(hb0[0], hb1[0], acc0, acc1, cre1, xv0, true, false);
    }
    __syncthreads();

    for (int t = 0; t < Tdim; ++t) {
        const int P  = t & 1;
        const int tn = (t + 1 < Tdim) ? (t + 1) : t;
        float xn0 = xp0[(size_t)tn * Pdim];   // for gemm_s0(t+1)

        // phase B(t): gemm_s1(t) reads hb1[P]  ||  ep_s0(t) writes hb0[P^1]
        phase(hb1[P], hb0[P ^ 1], acc1, acc0, cre0, xv1, true, true);
        __syncthreads();

        float xn1 = xp1[(size_t)tn * Pdim];   // for gemm_s1(t+1)
        if (t + 1 < Tdim) {
            // phase A(t+1): gemm_s0(t+1) reads hb0[P^1] || ep_s1(t) writes hb1[P^1]
            phase(hb0[P ^ 1], hb1[P ^ 1], acc0, acc1, cre1, xn0, true, true);
        } else {
            // final: ep_s1(95) only -> hb1[0]
            phase(hb0[P ^ 1], hb1[P ^ 1], acc0, acc1, cre1, 0.f, false, true);
        }
        __syncthreads();
        xv1 = xn1;
    }
    // final h: stream0 in hb0[0], stream1 in hb1[0] (swizzled layout)

    // ---- FC: out[b][o][p] = sum_k W_fc[p][o][k]*h[b][k] + b_fc[p][o] ----
    const float* wfc = W_fc + (size_t)p * Odim * Hdim;
    const float* bfc = b_fc + (size_t)p * Odim;
    for (int i = tid; i < Bdim * Odim; i += 1024) {
        int o = i % Odim;
        int b = i / Odim;            // global batch 0..63
        int bl = (b < BH) ? b : (b - BH);
        const unsigned short* hr = (b < BH) ? (hb0[0] + (bl << 7))
                                            : (hb1[0] + (bl << 7));
        float s = bfc[o];
        const float* wr = wfc + o * Hdim;
        #pragma unroll 8
        for (int k2 = 0; k2 < Hdim; ++k2) {
            int idx = (((k2 >> 3) ^ (bl & 15)) << 3) + (k2 & 7);   // unswizzle
            HS s2; s2.s = hr[idx];
            s = __builtin_fmaf(wr[k2], (float)s2.h, s);
        }
        out[(size_t)b * Odim * Pdim + (size_t)o * Pdim + p] = s;
    }
}

extern "C" void kernel_launch(void* const* d_in, const int* in_sizes, int n_in,
                              void* d_out, int out_size, void* d_ws, size_t ws_size,
                              hipStream_t stream) {
    const float* x    = (const float*)d_in[0];
    const float* W_ih = (const float*)d_in[1];
    const float* W_hh = (const float*)d_in[2];
    const float* b_ih = (const float*)d_in[3];
    const float* b_hh = (const float*)d_in[4];
    const float* W_fc = (const float*)d_in[5];
    const float* b_fc = (const float*)d_in[6];
    float* out = (float*)d_out;

    lstm_fused<<<dim3(Pdim), dim3(1024), 0, stream>>>(x, W_ih, W_hh, b_ih, b_hh, W_fc, b_fc, out);
}